// Round 7
// baseline (442.335 us; speedup 1.0000x reference)
//
#include <hip/hip_runtime.h>

typedef unsigned short ushort_t;
typedef __attribute__((ext_vector_type(8))) short short8;
typedef __attribute__((ext_vector_type(4))) float floatx4;

#define DD 256
#define LL 3
#define GG 4
#define KK 128
#define UU 64
#define OUTN 10
#define HSTRIDE 264   // fallback kernel only
#define BB 131072

__device__ __forceinline__ ushort_t f2bf(float f) {
  unsigned u = __builtin_bit_cast(unsigned, f);
  u = (u + 0x7FFFu + ((u >> 16) & 1u)) >> 16;
  return (ushort_t)u;
}

// pack two f32 -> two bf16 (lo in low half): 2 adds + 1 v_perm_b32
__device__ __forceinline__ unsigned pack_bf2(float lo, float hi) {
  unsigned a = __builtin_bit_cast(unsigned, hi) + 0x8000u;
  unsigned b = __builtin_bit_cast(unsigned, lo) + 0x8000u;
  return __builtin_amdgcn_perm(a, b, 0x07060302u);
}

// tanh(x) = 1 - 2/(e^{2x}+1); branch-free, exact at overflow
__device__ __forceinline__ float fast_tanh(float x) {
  float e = __builtin_amdgcn_exp2f(x * 2.885390081777927f);
  return __builtin_fmaf(-2.0f, __builtin_amdgcn_rcpf(e + 1.0f), 1.0f);
}

// AT[l][n][k] = sum_{j: idx[l,g,j]==k} W[l,g,j,u]  (n = g*64+u), bf16.
// WoT[n][k] = W_out[k][n] (n<10 else 0), 16x256 bf16.
__global__ __launch_bounds__(256) void prep_kernel(
    const int* __restrict__ idx, const float* __restrict__ W,
    const float* __restrict__ Wout, ushort_t* __restrict__ AT,
    ushort_t* __restrict__ WoT) {
  int b = blockIdx.x;
  int t = threadIdx.x;
  if (b < LL * DD) {
    int l = b >> 8, n = b & 255, g = n >> 6, u = n & 63;
    __shared__ int sidx[KK];
    __shared__ float sw[KK];
    if (t < KK) {
      sidx[t] = idx[(l * GG + g) * KK + t];
      sw[t]   = W[((size_t)((l * GG + g) * KK + t)) * UU + u];
    }
    __syncthreads();
    float s = 0.f;
#pragma unroll 8
    for (int j = 0; j < KK; j++) s += (sidx[j] == t) ? sw[j] : 0.f;
    AT[(b << 8) | t] = f2bf(s);
  } else {
    int e2 = (b - LL * DD) * 256 + t;
    int n = e2 >> 8, k = e2 & 255;
    WoT[e2] = (n < OUTN) ? f2bf(Wout[k * OUTN + n]) : (ushort_t)0;
  }
}

// ---------------- barrier-free level kernels ----------------
// Block: 512 thr = 8 waves as Wm(2) x Wn(4). Wave computes rows [wm*64, +64) x
// cols [wn*64, +64) of its 128-row block. No LDS, no __syncthreads.
// Operand-swap MFMA: D col=l16 -> local row, reg+quad*4 -> local col.

__global__ __launch_bounds__(512, 3) void level_f32(
    const float* __restrict__ xin, const float* __restrict__ bias,
    const ushort_t* __restrict__ A, ushort_t* __restrict__ hout) {
  const int tid  = threadIdx.x;
  const int wave = tid >> 6;
  const int wm   = wave >> 2;
  const int wn   = wave & 3;
  const int lane = tid & 63;
  const int quad = lane >> 4;
  const int l16  = lane & 15;
  const long row0 = (long)blockIdx.x * 128 + wm * 64;

  const float*    xrow = xin + (row0 + l16) * DD + quad * 8;        // + mt*16*DD + ks*32
  const ushort_t* Ab   = A + (wn * 64 + l16) * DD + quad * 8;      // + nt*16*DD + ks*32

  floatx4 acc[4][4];
#pragma unroll
  for (int nt = 0; nt < 4; nt++) {
    float4 bv = *(const float4*)&bias[wn * 64 + nt * 16 + quad * 4];
    floatx4 ini = {bv.x, bv.y, bv.z, bv.w};
#pragma unroll
    for (int mt = 0; mt < 4; mt++) acc[mt][nt] = ini;
  }

  short8 wf[4], wfn[4];
#pragma unroll
  for (int nt = 0; nt < 4; nt++) wf[nt] = *(const short8*)&Ab[nt * 16 * DD];

#pragma unroll
  for (int ks = 0; ks < 8; ks++) {
    if (ks < 7) {
#pragma unroll
      for (int nt = 0; nt < 4; nt++)
        wfn[nt] = *(const short8*)&Ab[nt * 16 * DD + (ks + 1) * 32];
    }
    short8 af[4];
#pragma unroll
    for (int mt = 0; mt < 4; mt++) {
      float4 v0 = *(const float4*)&xrow[mt * 16 * DD + ks * 32];
      float4 v1 = *(const float4*)&xrow[mt * 16 * DD + ks * 32 + 4];
      uint4 p;
      p.x = pack_bf2(v0.x, v0.y); p.y = pack_bf2(v0.z, v0.w);
      p.z = pack_bf2(v1.x, v1.y); p.w = pack_bf2(v1.z, v1.w);
      af[mt] = __builtin_bit_cast(short8, p);
    }
#pragma unroll
    for (int mt = 0; mt < 4; mt++)
#pragma unroll
      for (int nt = 0; nt < 4; nt++)
        acc[mt][nt] = __builtin_amdgcn_mfma_f32_16x16x32_bf16(wf[nt], af[mt], acc[mt][nt], 0, 0, 0);
#pragma unroll
    for (int nt = 0; nt < 4; nt++) wf[nt] = wfn[nt];
  }

#pragma unroll
  for (int mt = 0; mt < 4; mt++) {
    ushort_t* hrow = hout + (row0 + mt * 16 + l16) * DD + wn * 64 + quad * 4;
#pragma unroll
    for (int nt = 0; nt < 4; nt++) {
      uint2 w;
      w.x = pack_bf2(fast_tanh(acc[mt][nt][0]), fast_tanh(acc[mt][nt][1]));
      w.y = pack_bf2(fast_tanh(acc[mt][nt][2]), fast_tanh(acc[mt][nt][3]));
      *(uint2*)&hrow[nt * 16] = w;
    }
  }
}

__global__ __launch_bounds__(512, 3) void level_bf16(
    const ushort_t* __restrict__ hin, const float* __restrict__ bias,
    const ushort_t* __restrict__ A, ushort_t* __restrict__ hout) {
  const int tid  = threadIdx.x;
  const int wave = tid >> 6;
  const int wm   = wave >> 2;
  const int wn   = wave & 3;
  const int lane = tid & 63;
  const int quad = lane >> 4;
  const int l16  = lane & 15;
  const long row0 = (long)blockIdx.x * 128 + wm * 64;

  const ushort_t* hrow = hin + (row0 + l16) * DD + quad * 8;
  const ushort_t* Ab   = A + (wn * 64 + l16) * DD + quad * 8;

  floatx4 acc[4][4];
#pragma unroll
  for (int nt = 0; nt < 4; nt++) {
    float4 bv = *(const float4*)&bias[wn * 64 + nt * 16 + quad * 4];
    floatx4 ini = {bv.x, bv.y, bv.z, bv.w};
#pragma unroll
    for (int mt = 0; mt < 4; mt++) acc[mt][nt] = ini;
  }

  short8 wf[4], wfn[4], af[4], afn[4];
#pragma unroll
  for (int nt = 0; nt < 4; nt++) wf[nt] = *(const short8*)&Ab[nt * 16 * DD];
#pragma unroll
  for (int mt = 0; mt < 4; mt++) af[mt] = *(const short8*)&hrow[mt * 16 * DD];

#pragma unroll
  for (int ks = 0; ks < 8; ks++) {
    if (ks < 7) {
#pragma unroll
      for (int nt = 0; nt < 4; nt++)
        wfn[nt] = *(const short8*)&Ab[nt * 16 * DD + (ks + 1) * 32];
#pragma unroll
      for (int mt = 0; mt < 4; mt++)
        afn[mt] = *(const short8*)&hrow[mt * 16 * DD + (ks + 1) * 32];
    }
#pragma unroll
    for (int mt = 0; mt < 4; mt++)
#pragma unroll
      for (int nt = 0; nt < 4; nt++)
        acc[mt][nt] = __builtin_amdgcn_mfma_f32_16x16x32_bf16(wf[nt], af[mt], acc[mt][nt], 0, 0, 0);
#pragma unroll
    for (int nt = 0; nt < 4; nt++) wf[nt] = wfn[nt];
#pragma unroll
    for (int mt = 0; mt < 4; mt++) af[mt] = afn[mt];
  }

#pragma unroll
  for (int mt = 0; mt < 4; mt++) {
    ushort_t* orow = hout + (row0 + mt * 16 + l16) * DD + wn * 64 + quad * 4;
#pragma unroll
    for (int nt = 0; nt < 4; nt++) {
      uint2 w;
      w.x = pack_bf2(fast_tanh(acc[mt][nt][0]), fast_tanh(acc[mt][nt][1]));
      w.y = pack_bf2(fast_tanh(acc[mt][nt][2]), fast_tanh(acc[mt][nt][3]));
      *(uint2*)&orow[nt * 16] = w;
    }
  }
}

// final: out = h3 @ WoT^T + bout. One wave per 16 rows; no LDS, no barriers.
__global__ __launch_bounds__(512, 4) void final_kernel(
    const ushort_t* __restrict__ h3, const ushort_t* __restrict__ WoT,
    const float* __restrict__ bout, float* __restrict__ out) {
  const int tid  = threadIdx.x;
  const int wave = tid >> 6;
  const int lane = tid & 63;
  const int quad = lane >> 4;
  const int l16  = lane & 15;
  const long row = (long)blockIdx.x * 128 + wave * 16 + l16;

  const ushort_t* hrow = h3 + row * DD + quad * 8;

  short8 wof[8];
#pragma unroll
  for (int ks = 0; ks < 8; ks++)
    wof[ks] = *(const short8*)&WoT[l16 * DD + ks * 32 + quad * 8];

  floatx4 accf = {0.f, 0.f, 0.f, 0.f};
#pragma unroll
  for (int ks = 0; ks < 8; ks++) {
    short8 af = *(const short8*)&hrow[ks * 32];
    accf = __builtin_amdgcn_mfma_f32_16x16x32_bf16(wof[ks], af, accf, 0, 0, 0);
  }
  const long obase = row * OUTN;
  if (quad < 2) {
    float4 p = {accf[0] + bout[quad * 4 + 0], accf[1] + bout[quad * 4 + 1],
                accf[2] + bout[quad * 4 + 2], accf[3] + bout[quad * 4 + 3]};
    *(float4*)&out[obase + quad * 4] = p;
  } else if (quad == 2) {
    float2 p = {accf[0] + bout[8], accf[1] + bout[9]};
    *(float2*)&out[obase + 8] = p;
  }
}

// ---------------- fallback (R5 fused, used only if ws too small) ------------
__global__ __launch_bounds__(512, 4) void fused_fallback(
    const float* __restrict__ x, const float* __restrict__ bias,
    const float* __restrict__ bout, const ushort_t* __restrict__ AT,
    const ushort_t* __restrict__ WoT, float* __restrict__ out) {
  __shared__ ushort_t hbuf[128 * HSTRIDE];
  const int tid  = threadIdx.x;
  const int wave = tid >> 6;
  const int lane = tid & 63;
  const int quad = lane >> 4;
  const int l16  = lane & 15;
  const long row0 = (long)blockIdx.x * 128;

  const float4* xv = (const float4*)(x + row0 * DD);
#pragma unroll
  for (int i = 0; i < 16; i++) {
    int f  = tid + i * 512;
    int r  = f >> 6;
    int c4 = f & 63;
    float4 v = xv[r * 64 + c4];
    uint2 w;
    w.x = pack_bf2(v.x, v.y);
    w.y = pack_bf2(v.z, v.w);
    *(uint2*)&hbuf[r * HSTRIDE + c4 * 4] = w;
  }
  __syncthreads();

#pragma unroll 1
  for (int l = 0; l < 3; l++) {
    const ushort_t* Ab = AT + l * (DD * DD) + (wave * 32 + l16) * DD + quad * 8;
    const ushort_t* hsrc = hbuf + l16 * HSTRIDE + quad * 8;
    floatx4 acc[8][2];
#pragma unroll
    for (int nt = 0; nt < 2; nt++) {
      float4 bv = *(const float4*)&bias[l * DD + wave * 32 + nt * 16 + quad * 4];
      floatx4 ini = {bv.x, bv.y, bv.z, bv.w};
#pragma unroll
      for (int mt = 0; mt < 8; mt++) acc[mt][nt] = ini;
    }
    short8 wf[2], wfn[2];
#pragma unroll
    for (int nt = 0; nt < 2; nt++) wf[nt] = *(const short8*)&Ab[nt * 16 * DD];
#pragma unroll
    for (int ks = 0; ks < 8; ks++) {
      if (ks < 7) {
#pragma unroll
        for (int nt = 0; nt < 2; nt++)
          wfn[nt] = *(const short8*)&Ab[nt * 16 * DD + (ks + 1) * 32];
      }
      short8 bfc = *(const short8*)&hsrc[ks * 32];
#pragma unroll
      for (int mt = 0; mt < 8; mt++) {
        short8 bfn;
        if (mt < 7) bfn = *(const short8*)&hsrc[(mt + 1) * 16 * HSTRIDE + ks * 32];
        acc[mt][0] = __builtin_amdgcn_mfma_f32_16x16x32_bf16(wf[0], bfc, acc[mt][0], 0, 0, 0);
        acc[mt][1] = __builtin_amdgcn_mfma_f32_16x16x32_bf16(wf[1], bfc, acc[mt][1], 0, 0, 0);
        bfc = bfn;
      }
#pragma unroll
      for (int nt = 0; nt < 2; nt++) wf[nt] = wfn[nt];
    }
    __syncthreads();
#pragma unroll
    for (int nt = 0; nt < 2; nt++) {
#pragma unroll
      for (int mt = 0; mt < 8; mt++) {
        uint2 w;
        w.x = pack_bf2(fast_tanh(acc[mt][nt][0]), fast_tanh(acc[mt][nt][1]));
        w.y = pack_bf2(fast_tanh(acc[mt][nt][2]), fast_tanh(acc[mt][nt][3]));
        *(uint2*)&hbuf[(mt * 16 + l16) * HSTRIDE + wave * 32 + nt * 16 + quad * 4] = w;
      }
    }
    __syncthreads();
  }

  short8 wof[8];
#pragma unroll
  for (int ks = 0; ks < 8; ks++)
    wof[ks] = *(const short8*)&WoT[l16 * DD + ks * 32 + quad * 8];
  floatx4 accf = {0.f, 0.f, 0.f, 0.f};
#pragma unroll
  for (int ks = 0; ks < 8; ks++) {
    short8 bfr = *(const short8*)&hbuf[(wave * 16 + l16) * HSTRIDE + ks * 32 + quad * 8];
    accf = __builtin_amdgcn_mfma_f32_16x16x32_bf16(wof[ks], bfr, accf, 0, 0, 0);
  }
  const long obase = (row0 + wave * 16 + l16) * OUTN;
  if (quad < 2) {
    float4 p = {accf[0] + bout[quad * 4 + 0], accf[1] + bout[quad * 4 + 1],
                accf[2] + bout[quad * 4 + 2], accf[3] + bout[quad * 4 + 3]};
    *(float4*)&out[obase + quad * 4] = p;
  } else if (quad == 2) {
    float2 p = {accf[0] + bout[8], accf[1] + bout[9]};
    *(float2*)&out[obase + 8] = p;
  }
}

extern "C" void kernel_launch(void* const* d_in, const int* in_sizes, int n_in,
                              void* d_out, int out_size, void* d_ws, size_t ws_size,
                              hipStream_t stream) {
  const float* x    = (const float*)d_in[0];   // (131072, 256) fp32
  const int*   idx  = (const int*)d_in[1];     // (3, 4, 128) int32
  const float* W    = (const float*)d_in[2];   // (3, 4, 128, 64) fp32
  const float* b    = (const float*)d_in[3];   // (3, 4, 64) fp32
  const float* Wout = (const float*)d_in[4];   // (256, 10) fp32
  const float* bout = (const float*)d_in[5];   // (10,) fp32
  float* out = (float*)d_out;                  // (131072, 10) fp32

  ushort_t* AT  = (ushort_t*)d_ws;             // 3*256*256 bf16 = 393216 B
  ushort_t* WoT = AT + LL * DD * DD;           // 16*256 bf16 = 8192 B

  const size_t hbytes = (size_t)BB * DD * 2;   // 67108864
  const size_t base   = 393216 + 8192;         // 401408
  const size_t needed = base + 2 * hbytes;     // ~128.4 MiB

  prep_kernel<<<LL * DD + 16, 256, 0, stream>>>(idx, W, Wout, AT, WoT);

  if (ws_size >= needed) {
    ushort_t* hA = (ushort_t*)((char*)d_ws + base);
    ushort_t* hB = (ushort_t*)((char*)d_ws + base + hbytes);
    level_f32 <<<BB / 128, 512, 0, stream>>>(x,  b + 0 * DD, AT,                hA);
    level_bf16<<<BB / 128, 512, 0, stream>>>(hA, b + 1 * DD, AT + 1 * DD * DD,  hB);
    level_bf16<<<BB / 128, 512, 0, stream>>>(hB, b + 2 * DD, AT + 2 * DD * DD,  hA);
    final_kernel<<<BB / 128, 512, 0, stream>>>(hA, WoT, bout, out);
  } else {
    fused_fallback<<<BB / 128, 512, 0, stream>>>(x, b, bout, AT, WoT, out);
  }
}